// Round 2
// baseline (1740.792 us; speedup 1.0000x reference)
//
#include <hip/hip_runtime.h>
#include <hip/hip_bf16.h>
#include <math.h>

#define B_ 128
#define H_ 100
#define C_ 32
#define K_ 4
#define D_ 400
#define E_ 200
#define CW_ 100
#define N_ (B_*C_)
#define EPAD 224
#define DPAD 416

typedef short bf16x8 __attribute__((ext_vector_type(8)));
typedef float f32x4  __attribute__((ext_vector_type(4)));

__device__ __forceinline__ short f2b(float f) {
  union { float f; unsigned u; } x; x.f = f;
  unsigned r = x.u + 0x7fffu + ((x.u >> 16) & 1u);   // RNE (inputs well-behaved, no NaN)
  return (short)(r >> 16);
}

// ------------------------------------------------------------------
// k0: pre-cast W_att -> bf16, transposed + zero-padded: WT[k][e 224][d 416]
// ------------------------------------------------------------------
__global__ __launch_bounds__(256) void k0_cast(const float* __restrict__ W_att,
                                               short* __restrict__ WT) {
  const int idx = blockIdx.x * 256 + threadIdx.x;
  if (idx >= K_*EPAD*DPAD) return;
  const int d   = idx % DPAD;
  const int col = (idx / DPAD) % EPAD;
  const int k   = idx / (DPAD*EPAD);
  const float v = (d < D_ && col < E_) ? W_att[((size_t)k*D_ + d)*E_ + col] : 0.f;
  WT[idx] = f2b(v);
}

// ------------------------------------------------------------------
// k1: logits via bf16 MFMA. Per k: GEMM M=12800 (b,h), N=200(->208 used of
// 224 staged), Kdim=400(->416). Block = 4 waves x 16 rows = 64 rows.
// A_lds[64][40] bf16 (stride 40 shorts = 80 B: 16-B aligned, conflict-free
// for the b128 fragment pattern), B_lds[224][40] (B^T: col-major d-lines).
// frag layouts (16x16x32_bf16): A: row=l&15, k=8*(l>>4)+j; B: col=l&15,
// k=8*(l>>4)+j; C: col=l&15, row=4*(l>>4)+reg  [verified m89/m91].
// Epilogue: tanh(acc+b)*q, 16-lane shuffle reduce over cols.
// ------------------------------------------------------------------
__global__ __launch_bounds__(256) void k1_mfma(const float* __restrict__ his,
                                               const short* __restrict__ WT,
                                               const float* __restrict__ b_att,
                                               const float* __restrict__ q_att,
                                               float* __restrict__ logits) {
  const int mt = blockIdx.x, k = blockIdx.y;
  const int tid = threadIdx.x;
  const int wv = tid >> 6, l = tid & 63;
  const int ln16 = l & 15, g = l >> 4;
  const int m0 = mt * 64;
  __shared__ short Al[64][40];
  __shared__ short Bl[EPAD][40];

  f32x4 acc[13];
  #pragma unroll
  for (int nt = 0; nt < 13; ++nt) acc[nt] = (f32x4){0.f, 0.f, 0.f, 0.f};

  const short* WTk = WT + (size_t)k*EPAD*DPAD;

  for (int d0 = 0; d0 < DPAD; d0 += 32) {
    __syncthreads();
    // stage A: 64 rows x 32 d, fp32 -> bf16 (coalesced float4 loads)
    #pragma unroll
    for (int i = 0; i < 2; ++i) {
      const int idx = tid + i*256;
      const int row = idx >> 3, ch = idx & 7;
      const int d = d0 + ch*4;
      short4 s4 = {0, 0, 0, 0};
      if (d < D_) {
        const float4 a4 = *(const float4*)(his + ((size_t)(m0+row)*K_ + k)*D_ + d);
        s4.x = f2b(a4.x); s4.y = f2b(a4.y); s4.z = f2b(a4.z); s4.w = f2b(a4.w);
      }
      *(short4*)&Al[row][ch*4] = s4;
    }
    // stage B: 224 cols x 32 d (bf16, already transposed/padded)
    for (int idx = tid; idx < EPAD*4; idx += 256) {
      const int col = idx >> 2, ch = idx & 3;
      *(bf16x8*)&Bl[col][ch*8] = *(const bf16x8*)(WTk + (size_t)col*DPAD + d0 + ch*8);
    }
    __syncthreads();
    const bf16x8 af = *(const bf16x8*)&Al[wv*16 + ln16][g*8];
    #pragma unroll
    for (int nt = 0; nt < 13; ++nt) {
      const bf16x8 bf = *(const bf16x8*)&Bl[nt*16 + ln16][g*8];
      acc[nt] = __builtin_amdgcn_mfma_f32_16x16x32_bf16(af, bf, acc[nt], 0, 0, 0);
    }
  }

  // epilogue: p[reg] = sum_e tanh(acc+b)*q for rows 4g+reg of this wave's band
  float p[4] = {0.f, 0.f, 0.f, 0.f};
  #pragma unroll
  for (int nt = 0; nt < 13; ++nt) {
    const int e = nt*16 + ln16;
    float q = 0.f, bb = 0.f;
    if (e < E_) { q = q_att[k*E_ + e]; bb = b_att[k*E_ + e]; }
    #pragma unroll
    for (int reg = 0; reg < 4; ++reg)
      p[reg] += tanhf(acc[nt][reg] + bb) * q;
  }
  #pragma unroll
  for (int off = 1; off < 16; off <<= 1)
    #pragma unroll
    for (int reg = 0; reg < 4; ++reg) p[reg] += __shfl_xor(p[reg], off);
  if (ln16 == 0) {
    #pragma unroll
    for (int reg = 0; reg < 4; ++reg) {
      const int m = m0 + wv*16 + g*4 + reg;
      const int b = m / H_, h = m % H_;
      logits[(b*K_ + k)*H_ + h] = p[reg];
    }
  }
}

// ------------------------------------------------------------------
// k2: softmax over H + u_b = a.his + ulin = u_b.W_lin[:D] + b_lin (fused).
// fp32 throughout (precision-critical path).
// ------------------------------------------------------------------
__global__ __launch_bounds__(256) void k2_fused(const float* __restrict__ his,
                                                const float* __restrict__ logits,
                                                const float* __restrict__ W_lin,
                                                const float* __restrict__ b_lin,
                                                float* __restrict__ u_b,
                                                float* __restrict__ ulin) {
  const int b = blockIdx.x, k = blockIdx.y;
  const int tid = threadIdx.x;
  __shared__ float sv[128];
  __shared__ float sa[H_];
  __shared__ float ul[D_];
  __shared__ float half1[D_];

  float v = -INFINITY;
  if (tid < H_) v = logits[(b*K_ + k)*H_ + tid];
  if (tid < 128) sv[tid] = v;
  __syncthreads();
  for (int s = 64; s > 0; s >>= 1) { if (tid < s) sv[tid] = fmaxf(sv[tid], sv[tid+s]); __syncthreads(); }
  const float mx = sv[0];
  __syncthreads();
  const float ev = (tid < H_) ? expf(v - mx) : 0.f;
  if (tid < 128) sv[tid] = ev;
  __syncthreads();
  for (int s = 64; s > 0; s >>= 1) { if (tid < s) sv[tid] += sv[tid+s]; __syncthreads(); }
  const float inv = 1.f / sv[0];
  if (tid < H_) sa[tid] = ev * inv;
  __syncthreads();

  // u_b: float4 per thread, h-range split across two 100-thread groups
  const int gg = tid / 100;          // 0 or 1 (valid for tid<200)
  const int d4 = tid % 100;
  float4 a4 = {0.f, 0.f, 0.f, 0.f};
  if (tid < 200) {
    const float* hp = his + (((size_t)b*H_ + gg*50)*K_ + k)*D_ + d4*4;
    #pragma unroll 5
    for (int h = 0; h < 50; ++h) {
      const float4 x = *(const float4*)(hp + (size_t)h*K_*D_);
      const float w = sa[gg*50 + h];
      a4.x += w*x.x; a4.y += w*x.y; a4.z += w*x.z; a4.w += w*x.w;
    }
  }
  if (tid >= 100 && tid < 200) *(float4*)&half1[d4*4] = a4;
  __syncthreads();
  if (tid < 100) {
    const float4 o = *(const float4*)&half1[d4*4];
    a4.x += o.x; a4.y += o.y; a4.z += o.z; a4.w += o.w;
    *(float4*)&ul[d4*4] = a4;
    *(float4*)(u_b + ((size_t)b*K_ + k)*D_ + d4*4) = a4;
  }
  __syncthreads();

  // ulin: 200 cols, 4-way ILP accumulators, coalesced W_lin reads (L2-hot)
  if (tid < E_) {
    float a0 = b_lin[tid], a1 = 0.f, a2 = 0.f, a3 = 0.f;
    #pragma unroll 2
    for (int d = 0; d < D_; d += 4) {
      a0 += ul[d]   * W_lin[(size_t)d*E_     + tid];
      a1 += ul[d+1] * W_lin[(size_t)(d+1)*E_ + tid];
      a2 += ul[d+2] * W_lin[(size_t)(d+2)*E_ + tid];
      a3 += ul[d+3] * W_lin[(size_t)(d+3)*E_ + tid];
    }
    ulin[((size_t)b*K_ + k)*E_ + tid] = a0 + a1 + a2 + a3;
  }
}

// ------------------------------------------------------------------
// k4: per 8 candidates: score dots (float4), cl = cw @ W_lin[D:] with
// W2 LDS-chunked (4 x 25 rows), tanh+q_vec logits, softmax over K,
// final scores, u_channel broadcast write.
// ------------------------------------------------------------------
__global__ __launch_bounds__(256) void k4_combine(const float* __restrict__ cdd,
                                                  const float* __restrict__ cwt,
                                                  const float* __restrict__ W_lin,
                                                  const float* __restrict__ q_vec,
                                                  const float* __restrict__ u_b,
                                                  const float* __restrict__ ulin,
                                                  float* __restrict__ out) {
  const int n0 = blockIdx.x * 8;
  const int b  = n0 / C_;
  const int tid = threadIdx.x;
  const int pr = tid >> 5, pc = tid & 31;
  __shared__ float u_lds[K_*D_];
  __shared__ float cw_lds[8][K_][CW_ + 1];
  __shared__ float W2[25][E_];
  __shared__ float sc_lds[8][K_];
  __shared__ float lg_lds[8][K_];

  for (int idx = tid; idx < K_*D_; idx += 256) u_lds[idx] = u_b[(size_t)b*K_*D_ + idx];
  {
    const float* src = cwt + (size_t)n0*K_*CW_;
    for (int idx = tid; idx < 8*K_*CW_; idx += 256) {
      const int i = idx / (K_*CW_), rem = idx % (K_*CW_);
      cw_lds[i][rem / CW_][rem % CW_] = src[idx];
    }
  }
  __syncthreads();

  // candidate scores: 32 length-400 dots, float4, one per wave-slot
  {
    const int wvv = tid >> 6, lnn = tid & 63;
    for (int p = wvv; p < 8*K_; p += 4) {
      const int i = p >> 2, kk = p & 3;
      const float* cp = cdd + ((size_t)(n0 + i)*K_ + kk)*D_;
      float accs = 0.f;
      for (int dd = lnn; dd < 100; dd += 64) {
        const float4 c4 = *(const float4*)(cp + dd*4);
        const float4 u4 = *(const float4*)&u_lds[kk*D_ + dd*4];
        accs += c4.x*u4.x + c4.y*u4.y + c4.z*u4.z + c4.w*u4.w;
      }
      #pragma unroll
      for (int off = 32; off >= 1; off >>= 1) accs += __shfl_down(accs, off);
      if (lnn == 0) sc_lds[i][kk] = accs;
    }
  }

  // cl[kk][e] = sum_c cw[n,kk,c] * W_lin[D+c, e], W2 chunked through LDS
  float acc[K_][7];
  #pragma unroll
  for (int kk = 0; kk < K_; ++kk)
    #pragma unroll
    for (int j = 0; j < 7; ++j) acc[kk][j] = 0.f;

  for (int chb = 0; chb < 4; ++chb) {
    __syncthreads();
    for (int idx = tid; idx < 25*E_; idx += 256)
      W2[idx / E_][idx % E_] = W_lin[(size_t)(D_ + chb*25 + idx/E_)*E_ + idx % E_];
    __syncthreads();
    for (int c = 0; c < 25; ++c) {
      float w[7];
      #pragma unroll
      for (int j = 0; j < 7; ++j) { const int e = pc + 32*j; w[j] = (e < E_) ? W2[c][e] : 0.f; }
      #pragma unroll
      for (int kk = 0; kk < K_; ++kk) {
        const float a = cw_lds[pr][kk][chb*25 + c];
        #pragma unroll
        for (int j = 0; j < 7; ++j) acc[kk][j] += a * w[j];
      }
    }
  }

  // logits + reduce over pc
  float pl[K_] = {0.f, 0.f, 0.f, 0.f};
  #pragma unroll
  for (int j = 0; j < 7; ++j) {
    const int e = pc + 32*j;
    if (e < E_) {
      const float q = q_vec[e];
      #pragma unroll
      for (int kk = 0; kk < K_; ++kk)
        pl[kk] += tanhf(ulin[((size_t)b*K_ + kk)*E_ + e] + acc[kk][j]) * q;
    }
  }
  #pragma unroll
  for (int off = 16; off >= 1; off >>= 1)
    #pragma unroll
    for (int kk = 0; kk < K_; ++kk) pl[kk] += __shfl_xor(pl[kk], off);
  if (pc == 0) {
    #pragma unroll
    for (int kk = 0; kk < K_; ++kk) lg_lds[pr][kk] = pl[kk];
  }
  __syncthreads();

  if (tid < 8) {
    const float l0 = lg_lds[tid][0], l1 = lg_lds[tid][1];
    const float l2 = lg_lds[tid][2], l3 = lg_lds[tid][3];
    const float m = fmaxf(fmaxf(l0, l1), fmaxf(l2, l3));
    const float e0 = expf(l0 - m), e1 = expf(l1 - m);
    const float e2 = expf(l2 - m), e3 = expf(l3 - m);
    const float s = e0 + e1 + e2 + e3;
    out[n0 + tid] = (e0*sc_lds[tid][0] + e1*sc_lds[tid][1] +
                     e2*sc_lds[tid][2] + e3*sc_lds[tid][3]) / s;
  }

  float* uo = out + N_ + (size_t)n0*K_*D_;
  for (int idx = tid; idx < 8*K_*D_; idx += 256) uo[idx] = u_lds[idx % (K_*D_)];
}

extern "C" void kernel_launch(void* const* d_in, const int* in_sizes, int n_in,
                              void* d_out, int out_size, void* d_ws, size_t ws_size,
                              hipStream_t stream) {
  const float* his   = (const float*)d_in[0];
  const float* cdd   = (const float*)d_in[1];
  const float* cwt   = (const float*)d_in[2];
  const float* W_att = (const float*)d_in[3];
  const float* b_att = (const float*)d_in[4];
  const float* q_att = (const float*)d_in[5];
  const float* W_lin = (const float*)d_in[6];
  const float* b_lin = (const float*)d_in[7];
  const float* q_vec = (const float*)d_in[8];
  float* out = (float*)d_out;

  float* ws     = (float*)d_ws;
  float* logits = ws;                                   // B*K*H   = 51200 f
  float* u_b    = ws + (size_t)B_*K_*H_;                // B*K*D   = 204800 f
  float* ulin   = u_b + (size_t)B_*K_*D_;               // B*K*E   = 102400 f
  short* WT     = (short*)(ulin + (size_t)B_*K_*E_);    // 4*224*416 bf16

  k0_cast   <<<(K_*EPAD*DPAD + 255)/256, 256, 0, stream>>>(W_att, WT);
  k1_mfma   <<<dim3((B_*H_)/64, K_), 256, 0, stream>>>(his, WT, b_att, q_att, logits);
  k2_fused  <<<dim3(B_, K_),         256, 0, stream>>>(his, logits, W_lin, b_lin, u_b, ulin);
  k4_combine<<<N_/8,                 256, 0, stream>>>(cdd, cwt, W_lin, q_vec, u_b, ulin, out);
}

// Round 3
// 282.685 us; speedup vs baseline: 6.1581x; 6.1581x over previous
//
#include <hip/hip_runtime.h>
#include <hip/hip_bf16.h>
#include <math.h>

#define B_ 128
#define H_ 100
#define C_ 32
#define K_ 4
#define D_ 400
#define E_ 200
#define CW_ 100
#define N_ (B_*C_)
#define EPAD 224
#define DPAD 416

typedef short bf16x8 __attribute__((ext_vector_type(8)));
typedef float f32x4  __attribute__((ext_vector_type(4)));

__device__ __forceinline__ short f2b(float f) {
  union { float f; unsigned u; } x; x.f = f;
  unsigned r = x.u + 0x7fffu + ((x.u >> 16) & 1u);   // RNE (inputs well-behaved, no NaN)
  return (short)(r >> 16);
}

// ------------------------------------------------------------------
// k0: pre-cast W_att -> bf16, transposed + zero-padded: WT[k][e 224][d 416]
// ------------------------------------------------------------------
__global__ __launch_bounds__(256) void k0_cast(const float* __restrict__ W_att,
                                               short* __restrict__ WT) {
  const int idx = blockIdx.x * 256 + threadIdx.x;
  if (idx >= K_*EPAD*DPAD) return;
  const int d   = idx % DPAD;
  const int col = (idx / DPAD) % EPAD;
  const int k   = idx / (DPAD*EPAD);
  const float v = (d < D_ && col < E_) ? W_att[((size_t)k*D_ + d)*E_ + col] : 0.f;
  WT[idx] = f2b(v);
}

// ------------------------------------------------------------------
// k1: logits via bf16 MFMA (16x16x32). Unchanged from R2 (passed absmax).
// ------------------------------------------------------------------
__global__ __launch_bounds__(256) void k1_mfma(const float* __restrict__ his,
                                               const short* __restrict__ WT,
                                               const float* __restrict__ b_att,
                                               const float* __restrict__ q_att,
                                               float* __restrict__ logits) {
  const int mt = blockIdx.x, k = blockIdx.y;
  const int tid = threadIdx.x;
  const int wv = tid >> 6, l = tid & 63;
  const int ln16 = l & 15, g = l >> 4;
  const int m0 = mt * 64;
  __shared__ short Al[64][40];
  __shared__ short Bl[EPAD][40];

  f32x4 acc[13];
  #pragma unroll
  for (int nt = 0; nt < 13; ++nt) acc[nt] = (f32x4){0.f, 0.f, 0.f, 0.f};

  const short* WTk = WT + (size_t)k*EPAD*DPAD;

  for (int d0 = 0; d0 < DPAD; d0 += 32) {
    __syncthreads();
    #pragma unroll
    for (int i = 0; i < 2; ++i) {
      const int idx = tid + i*256;
      const int row = idx >> 3, ch = idx & 7;
      const int d = d0 + ch*4;
      short4 s4 = {0, 0, 0, 0};
      if (d < D_) {
        const float4 a4 = *(const float4*)(his + ((size_t)(m0+row)*K_ + k)*D_ + d);
        s4.x = f2b(a4.x); s4.y = f2b(a4.y); s4.z = f2b(a4.z); s4.w = f2b(a4.w);
      }
      *(short4*)&Al[row][ch*4] = s4;
    }
    for (int idx = tid; idx < EPAD*4; idx += 256) {
      const int col = idx >> 2, ch = idx & 3;
      *(bf16x8*)&Bl[col][ch*8] = *(const bf16x8*)(WTk + (size_t)col*DPAD + d0 + ch*8);
    }
    __syncthreads();
    const bf16x8 af = *(const bf16x8*)&Al[wv*16 + ln16][g*8];
    #pragma unroll
    for (int nt = 0; nt < 13; ++nt) {
      const bf16x8 bf = *(const bf16x8*)&Bl[nt*16 + ln16][g*8];
      acc[nt] = __builtin_amdgcn_mfma_f32_16x16x32_bf16(af, bf, acc[nt], 0, 0, 0);
    }
  }

  float p[4] = {0.f, 0.f, 0.f, 0.f};
  #pragma unroll
  for (int nt = 0; nt < 13; ++nt) {
    const int e = nt*16 + ln16;
    float q = 0.f, bb = 0.f;
    if (e < E_) { q = q_att[k*E_ + e]; bb = b_att[k*E_ + e]; }
    #pragma unroll
    for (int reg = 0; reg < 4; ++reg)
      p[reg] += tanhf(acc[nt][reg] + bb) * q;
  }
  #pragma unroll
  for (int off = 1; off < 16; off <<= 1)
    #pragma unroll
    for (int reg = 0; reg < 4; ++reg) p[reg] += __shfl_xor(p[reg], off);
  if (ln16 == 0) {
    #pragma unroll
    for (int reg = 0; reg < 4; ++reg) {
      const int m = m0 + wv*16 + g*4 + reg;
      const int b = m / H_, h = m % H_;
      logits[(b*K_ + k)*H_ + h] = p[reg];
    }
  }
}

// ------------------------------------------------------------------
// k2: softmax over H + u_b = a.his (h split 4x25) + ulin = u_b.W_lin[:D]+b_lin
// ------------------------------------------------------------------
__global__ __launch_bounds__(512) void k2_fused(const float* __restrict__ his,
                                                const float* __restrict__ logits,
                                                const float* __restrict__ W_lin,
                                                const float* __restrict__ b_lin,
                                                float* __restrict__ u_b,
                                                float* __restrict__ ulin) {
  const int b = blockIdx.x, k = blockIdx.y;
  const int tid = threadIdx.x;
  __shared__ float sv[128];
  __shared__ float sa[H_];
  __shared__ float4 part[4][100];
  __shared__ float ul[D_];

  float v = -INFINITY;
  if (tid < H_) v = logits[(b*K_ + k)*H_ + tid];
  if (tid < 128) sv[tid] = v;
  __syncthreads();
  for (int s = 64; s > 0; s >>= 1) { if (tid < s) sv[tid] = fmaxf(sv[tid], sv[tid+s]); __syncthreads(); }
  const float mx = sv[0];
  __syncthreads();
  const float ev = (tid < H_) ? expf(v - mx) : 0.f;
  if (tid < 128) sv[tid] = ev;
  __syncthreads();
  for (int s = 64; s > 0; s >>= 1) { if (tid < s) sv[tid] += sv[tid+s]; __syncthreads(); }
  const float inv = 1.f / sv[0];
  if (tid < H_) sa[tid] = ev * inv;
  __syncthreads();

  // u_b partials: 400 threads, gg = h-quarter (0..3), d4 = float4 index (0..99)
  const int gg = tid / 100;
  const int d4 = tid % 100;
  if (tid < 400) {
    float4 a4 = {0.f, 0.f, 0.f, 0.f};
    const float* hp = his + (((size_t)b*H_ + gg*25)*K_ + k)*D_ + d4*4;
    #pragma unroll 5
    for (int h = 0; h < 25; ++h) {
      const float4 x = *(const float4*)(hp + (size_t)h*K_*D_);
      const float w = sa[gg*25 + h];
      a4.x += w*x.x; a4.y += w*x.y; a4.z += w*x.z; a4.w += w*x.w;
    }
    part[gg][d4] = a4;
  }
  __syncthreads();
  if (tid < 100) {
    const float4 p0 = part[0][tid], p1 = part[1][tid], p2 = part[2][tid], p3 = part[3][tid];
    float4 a4;
    a4.x = p0.x+p1.x+p2.x+p3.x; a4.y = p0.y+p1.y+p2.y+p3.y;
    a4.z = p0.z+p1.z+p2.z+p3.z; a4.w = p0.w+p1.w+p2.w+p3.w;
    *(float4*)&ul[tid*4] = a4;
    *(float4*)(u_b + ((size_t)b*K_ + k)*D_ + tid*4) = a4;
  }
  __syncthreads();

  // ulin: 200 cols, 4-way ILP, coalesced W_lin (L2-hot)
  if (tid < E_) {
    float a0 = b_lin[tid], a1 = 0.f, a2 = 0.f, a3 = 0.f;
    #pragma unroll 2
    for (int d = 0; d < D_; d += 4) {
      a0 += ul[d]   * W_lin[(size_t)d*E_     + tid];
      a1 += ul[d+1] * W_lin[(size_t)(d+1)*E_ + tid];
      a2 += ul[d+2] * W_lin[(size_t)(d+2)*E_ + tid];
      a3 += ul[d+3] * W_lin[(size_t)(d+3)*E_ + tid];
    }
    ulin[((size_t)b*K_ + k)*E_ + tid] = a0 + a1 + a2 + a3;
  }
}

// ------------------------------------------------------------------
// k4: one block per candidate n. Tiny per-thread state (acc[4]) -> no spill.
//  - scores: wave w owns k=w, float4 dot over D, shuffle reduce
//  - cl[k][e]: thread e<200 accumulates over c (cw in LDS broadcast,
//    W_lin coalesced from L2)
//  - logits: tanh(ulin+cl)*q_vec, wave shuffle + cross-wave LDS reduce
//  - softmax over K, final score, u_channel slice write
// ------------------------------------------------------------------
__global__ __launch_bounds__(256) void k4_score(const float* __restrict__ cdd,
                                                const float* __restrict__ cwt,
                                                const float* __restrict__ W_lin,
                                                const float* __restrict__ q_vec,
                                                const float* __restrict__ u_b,
                                                const float* __restrict__ ulin,
                                                float* __restrict__ out) {
  const int n = blockIdx.x;
  const int b = n >> 5;                  // C_ = 32
  const int tid = threadIdx.x;
  const int wv = tid >> 6, ln = tid & 63;
  __shared__ float cw[K_][CW_];
  __shared__ float red[4][K_];
  __shared__ float sc[K_];

  for (int idx = tid; idx < K_*CW_; idx += 256)
    cw[idx / CW_][idx % CW_] = cwt[(size_t)n*K_*CW_ + idx];
  __syncthreads();

  // candidate score for k = wv
  {
    const float4* up = (const float4*)(u_b + ((size_t)b*K_ + wv)*D_);
    const float4* cp = (const float4*)(cdd + ((size_t)n*K_ + wv)*D_);
    float s = 0.f;
    for (int dd = ln; dd < 100; dd += 64) {
      const float4 u = up[dd], c = cp[dd];
      s += u.x*c.x + u.y*c.y + u.z*c.z + u.w*c.w;
    }
    #pragma unroll
    for (int off = 32; off >= 1; off >>= 1) s += __shfl_down(s, off);
    if (ln == 0) sc[wv] = s;
  }

  // cl + logit partials
  float pl0 = 0.f, pl1 = 0.f, pl2 = 0.f, pl3 = 0.f;
  if (tid < E_) {
    const int e = tid;
    float a0 = 0.f, a1 = 0.f, a2 = 0.f, a3 = 0.f;
    #pragma unroll 4
    for (int c = 0; c < CW_; ++c) {
      const float w = W_lin[(size_t)(D_ + c)*E_ + e];
      a0 += cw[0][c]*w; a1 += cw[1][c]*w; a2 += cw[2][c]*w; a3 += cw[3][c]*w;
    }
    const float q = q_vec[e];
    const float* ue = ulin + (size_t)b*K_*E_ + e;
    pl0 = tanhf(ue[0*E_] + a0) * q;
    pl1 = tanhf(ue[1*E_] + a1) * q;
    pl2 = tanhf(ue[2*E_] + a2) * q;
    pl3 = tanhf(ue[3*E_] + a3) * q;
  }
  #pragma unroll
  for (int off = 1; off < 64; off <<= 1) {
    pl0 += __shfl_xor(pl0, off); pl1 += __shfl_xor(pl1, off);
    pl2 += __shfl_xor(pl2, off); pl3 += __shfl_xor(pl3, off);
  }
  if (ln == 0) { red[wv][0] = pl0; red[wv][1] = pl1; red[wv][2] = pl2; red[wv][3] = pl3; }
  __syncthreads();

  if (tid == 0) {
    const float l0 = red[0][0]+red[1][0]+red[2][0]+red[3][0];
    const float l1 = red[0][1]+red[1][1]+red[2][1]+red[3][1];
    const float l2 = red[0][2]+red[1][2]+red[2][2]+red[3][2];
    const float l3 = red[0][3]+red[1][3]+red[2][3]+red[3][3];
    const float m = fmaxf(fmaxf(l0, l1), fmaxf(l2, l3));
    const float e0 = expf(l0 - m), e1 = expf(l1 - m);
    const float e2 = expf(l2 - m), e3 = expf(l3 - m);
    const float s = e0 + e1 + e2 + e3;
    out[n] = (e0*sc[0] + e1*sc[1] + e2*sc[2] + e3*sc[3]) / s;
  }

  // u_channel slice: broadcast u_b[b] (400 float4)
  {
    const float4* ub4 = (const float4*)(u_b + (size_t)b*K_*D_);
    float4* uo = (float4*)(out + N_ + (size_t)n*K_*D_);
    for (int idx = tid; idx < 400; idx += 256) uo[idx] = ub4[idx];
  }
}

extern "C" void kernel_launch(void* const* d_in, const int* in_sizes, int n_in,
                              void* d_out, int out_size, void* d_ws, size_t ws_size,
                              hipStream_t stream) {
  const float* his   = (const float*)d_in[0];
  const float* cdd   = (const float*)d_in[1];
  const float* cwt   = (const float*)d_in[2];
  const float* W_att = (const float*)d_in[3];
  const float* b_att = (const float*)d_in[4];
  const float* q_att = (const float*)d_in[5];
  const float* W_lin = (const float*)d_in[6];
  const float* b_lin = (const float*)d_in[7];
  const float* q_vec = (const float*)d_in[8];
  float* out = (float*)d_out;

  float* ws     = (float*)d_ws;
  float* logits = ws;                                   // B*K*H   = 51200 f
  float* u_b    = ws + (size_t)B_*K_*H_;                // B*K*D   = 204800 f
  float* ulin   = u_b + (size_t)B_*K_*D_;               // B*K*E   = 102400 f
  short* WT     = (short*)(ulin + (size_t)B_*K_*E_);    // 4*224*416 bf16

  k0_cast  <<<(K_*EPAD*DPAD + 255)/256, 256, 0, stream>>>(W_att, WT);
  k1_mfma  <<<dim3((B_*H_)/64, K_), 256, 0, stream>>>(his, WT, b_att, q_att, logits);
  k2_fused <<<dim3(B_, K_),         512, 0, stream>>>(his, logits, W_lin, b_lin, u_b, ulin);
  k4_score <<<N_,                   256, 0, stream>>>(cdd, cwt, W_lin, q_vec, u_b, ulin, out);
}

// Round 4
// 252.164 us; speedup vs baseline: 6.9034x; 1.1210x over previous
//
#include <hip/hip_runtime.h>
#include <hip/hip_bf16.h>
#include <math.h>

#define B_ 128
#define H_ 100
#define C_ 32
#define K_ 4
#define D_ 400
#define E_ 200
#define CW_ 100
#define N_ (B_*C_)
#define NCH 13            // K-chunks of 32 (416 padded)
#define NTI 13            // N-tiles of 16 (208 padded)
#define MR_ 112           // rows per block (100 valid + 12 pad)

typedef short bf16x8 __attribute__((ext_vector_type(8)));
typedef float f32x4  __attribute__((ext_vector_type(4)));

__device__ __forceinline__ short f2b(float f) {
  union { float f; unsigned u; } x; x.f = f;
  unsigned r = x.u + 0x7fffu + ((x.u >> 16) & 1u);   // RNE
  return (short)(r >> 16);
}

__device__ __forceinline__ void gload_lds16(const void* g, void* l) {
  __builtin_amdgcn_global_load_lds((const __attribute__((address_space(1))) void*)g,
                                   (__attribute__((address_space(3))) void*)l, 16, 0, 0);
}

// ------------------------------------------------------------------
// k0: W_att -> WT bf16, chunk-major pre-swizzled [k][c 13][col 208][j 40]
// (j = d-in-chunk, 32 valid + 8 zero pad; col 200..207 zero) so k12 can
// DMA each 16640-B chunk linearly into LDS with global_load_lds.
// ------------------------------------------------------------------
__global__ __launch_bounds__(256) void k0_cast(const float* __restrict__ W_att,
                                               short* __restrict__ WT) {
  const int k = blockIdx.x, c = blockIdx.y;
  const int tid = threadIdx.x;
  __shared__ float Wst[32][200];
  for (int idx = tid; idx < 32*200; idx += 256) {
    const int j = idx / 200, col = idx % 200;
    const int d = c*32 + j;
    Wst[j][col] = (d < D_) ? W_att[((size_t)k*D_ + d)*E_ + col] : 0.f;
  }
  __syncthreads();
  short* dst = WT + (size_t)(k*NCH + c)*208*40;
  for (int idx = tid; idx < 208*40; idx += 256) {
    const int col = idx / 40, j = idx % 40;
    const float v = (col < E_ && j < 32) ? Wst[j][col] : 0.f;
    dst[idx] = f2b(v);
  }
}

// ------------------------------------------------------------------
// k12: per (b,k): MFMA logits GEMM (M=112, N=208, K=416) + in-block
// softmax + u_b + ulin. 8 waves; wave w<7 owns M-tile w (16 rows).
// LDS double-buffered: A reg-staged (fp32->bf16), B via global_load_lds.
// ------------------------------------------------------------------
__global__ __launch_bounds__(512) void k12_fused(const float* __restrict__ his,
                                                 const short* __restrict__ WT,
                                                 const float* __restrict__ b_att,
                                                 const float* __restrict__ q_att,
                                                 const float* __restrict__ W_lin,
                                                 const float* __restrict__ b_lin,
                                                 float* __restrict__ u_b,
                                                 float* __restrict__ ulin) {
  const int b = blockIdx.x, k = blockIdx.y;
  const int tid = threadIdx.x;
  const int w = tid >> 6, l = tid & 63;
  const int ln16 = l & 15, g = l >> 4;

  __shared__ __align__(16) short Al[2][MR_][40];   // 2 x 8960 B
  __shared__ __align__(16) short Bl[2][208][40];   // 2 x 16640 B
  __shared__ float sl[MR_];
  __shared__ float sv[128];
  __shared__ float sa[H_];
  __shared__ float4 part[4][100];
  __shared__ float ul[D_];

  f32x4 acc[NTI];
  #pragma unroll
  for (int nt = 0; nt < NTI; ++nt) acc[nt] = (f32x4){0.f, 0.f, 0.f, 0.f};

  // A staging assignment: 448 threads, row = tid>>2 (0..111), q = tid&3
  const int arow = tid >> 2, aq = tid & 3;
  const bool astage = (tid < 448);
  const float* hisrow = his + (((size_t)b*H_ + arow)*K_ + k)*D_;
  const short* WTk = WT + (size_t)k*NCH*208*40;

  float4 a0, a1;
  // ---- prologue: stage chunk 0 into buf 0 ----
  {
    const int d = 0 + aq*8;
    a0 = (float4){0,0,0,0}; a1 = a0;
    if (astage && arow < H_ && d < D_) {
      a0 = *(const float4*)(hisrow + d);
      a1 = *(const float4*)(hisrow + d + 4);
    }
    const short* src = WTk;   // chunk 0
    for (int i = tid; i < 1040; i += 512)
      gload_lds16(src + i*8, (short*)&Bl[0][0][0] + i*8);
    if (astage) {
      short s8[8];
      s8[0]=f2b(a0.x); s8[1]=f2b(a0.y); s8[2]=f2b(a0.z); s8[3]=f2b(a0.w);
      s8[4]=f2b(a1.x); s8[5]=f2b(a1.y); s8[6]=f2b(a1.z); s8[7]=f2b(a1.w);
      *(bf16x8*)&Al[0][arow][aq*8] = *(bf16x8*)s8;
    }
  }
  __syncthreads();

  // ---- main loop over K-chunks ----
  int buf = 0;
  for (int c = 0; c < NCH; ++c) {
    const int nb = buf ^ 1;
    const bool more = (c + 1 < NCH);
    if (more) {
      const int d = (c+1)*32 + aq*8;
      a0 = (float4){0,0,0,0}; a1 = a0;
      if (astage && arow < H_ && d < D_) {
        a0 = *(const float4*)(hisrow + d);
        a1 = *(const float4*)(hisrow + d + 4);
      }
      const short* src = WTk + (size_t)(c+1)*208*40;
      for (int i = tid; i < 1040; i += 512)
        gload_lds16(src + i*8, (short*)&Bl[nb][0][0] + i*8);
    }
    // compute chunk c
    if (w < 7) {
      const bf16x8 af = *(const bf16x8*)&Al[buf][w*16 + ln16][g*8];
      #pragma unroll
      for (int nt = 0; nt < NTI; ++nt) {
        const bf16x8 bf = *(const bf16x8*)&Bl[buf][nt*16 + ln16][g*8];
        acc[nt] = __builtin_amdgcn_mfma_f32_16x16x32_bf16(af, bf, acc[nt], 0, 0, 0);
      }
    }
    if (more && astage) {
      short s8[8];
      s8[0]=f2b(a0.x); s8[1]=f2b(a0.y); s8[2]=f2b(a0.z); s8[3]=f2b(a0.w);
      s8[4]=f2b(a1.x); s8[5]=f2b(a1.y); s8[6]=f2b(a1.z); s8[7]=f2b(a1.w);
      *(bf16x8*)&Al[nb][arow][aq*8] = *(bf16x8*)s8;
    }
    __syncthreads();
    buf = nb;
  }

  // ---- epilogue: logits = sum_e tanh(acc + b_att)*q_att ----
  if (w < 7) {
    float p[4] = {0.f, 0.f, 0.f, 0.f};
    #pragma unroll
    for (int nt = 0; nt < NTI; ++nt) {
      const int e = nt*16 + ln16;
      float q = 0.f, bb = 0.f;
      if (e < E_) { q = q_att[k*E_ + e]; bb = b_att[k*E_ + e]; }
      #pragma unroll
      for (int reg = 0; reg < 4; ++reg)
        p[reg] += tanhf(acc[nt][reg] + bb) * q;
    }
    #pragma unroll
    for (int off = 1; off < 16; off <<= 1)
      #pragma unroll
      for (int reg = 0; reg < 4; ++reg) p[reg] += __shfl_xor(p[reg], off);
    if (ln16 == 0) {
      #pragma unroll
      for (int reg = 0; reg < 4; ++reg) sl[w*16 + g*4 + reg] = p[reg];
    }
  }
  __syncthreads();

  // ---- softmax over h<100 ----
  const float v = (tid < H_) ? sl[tid] : -INFINITY;
  if (tid < 128) sv[tid] = v;
  __syncthreads();
  for (int s = 64; s > 0; s >>= 1) { if (tid < s) sv[tid] = fmaxf(sv[tid], sv[tid+s]); __syncthreads(); }
  const float mx = sv[0];
  __syncthreads();
  const float ev = (tid < H_) ? expf(v - mx) : 0.f;
  if (tid < 128) sv[tid] = ev;
  __syncthreads();
  for (int s = 64; s > 0; s >>= 1) { if (tid < s) sv[tid] += sv[tid+s]; __syncthreads(); }
  const float inv = 1.f / sv[0];
  if (tid < H_) sa[tid] = ev * inv;
  __syncthreads();

  // ---- u_b = a . his (fp32, L2-hot re-read), 4 h-groups x 25 ----
  const int gg = tid / 100, d4 = tid % 100;
  if (tid < 400) {
    float4 a4 = {0.f, 0.f, 0.f, 0.f};
    const float* hp = his + (((size_t)b*H_ + gg*25)*K_ + k)*D_ + d4*4;
    #pragma unroll 5
    for (int h = 0; h < 25; ++h) {
      const float4 x = *(const float4*)(hp + (size_t)h*K_*D_);
      const float ww = sa[gg*25 + h];
      a4.x += ww*x.x; a4.y += ww*x.y; a4.z += ww*x.z; a4.w += ww*x.w;
    }
    part[gg][d4] = a4;
  }
  __syncthreads();
  if (tid < 100) {
    const float4 p0 = part[0][tid], p1 = part[1][tid], p2 = part[2][tid], p3 = part[3][tid];
    float4 a4;
    a4.x = p0.x+p1.x+p2.x+p3.x; a4.y = p0.y+p1.y+p2.y+p3.y;
    a4.z = p0.z+p1.z+p2.z+p3.z; a4.w = p0.w+p1.w+p2.w+p3.w;
    *(float4*)&ul[tid*4] = a4;
    *(float4*)(u_b + ((size_t)b*K_ + k)*D_ + tid*4) = a4;
  }
  __syncthreads();

  // ---- ulin = u_b . W_lin[:D] + b_lin ----
  if (tid < E_) {
    float c0 = b_lin[tid], c1 = 0.f, c2 = 0.f, c3 = 0.f;
    #pragma unroll 2
    for (int d = 0; d < D_; d += 4) {
      c0 += ul[d]   * W_lin[(size_t)d*E_     + tid];
      c1 += ul[d+1] * W_lin[(size_t)(d+1)*E_ + tid];
      c2 += ul[d+2] * W_lin[(size_t)(d+2)*E_ + tid];
      c3 += ul[d+3] * W_lin[(size_t)(d+3)*E_ + tid];
    }
    ulin[((size_t)b*K_ + k)*E_ + tid] = c0 + c1 + c2 + c3;
  }
}

// ------------------------------------------------------------------
// k4: one block per candidate n (unchanged from R3 — lean, no spill)
// ------------------------------------------------------------------
__global__ __launch_bounds__(256) void k4_score(const float* __restrict__ cdd,
                                                const float* __restrict__ cwt,
                                                const float* __restrict__ W_lin,
                                                const float* __restrict__ q_vec,
                                                const float* __restrict__ u_b,
                                                const float* __restrict__ ulin,
                                                float* __restrict__ out) {
  const int n = blockIdx.x;
  const int b = n >> 5;                  // C_ = 32
  const int tid = threadIdx.x;
  const int wv = tid >> 6, ln = tid & 63;
  __shared__ float cw[K_][CW_];
  __shared__ float red[4][K_];
  __shared__ float sc[K_];

  for (int idx = tid; idx < K_*CW_; idx += 256)
    cw[idx / CW_][idx % CW_] = cwt[(size_t)n*K_*CW_ + idx];
  __syncthreads();

  {
    const float4* up = (const float4*)(u_b + ((size_t)b*K_ + wv)*D_);
    const float4* cp = (const float4*)(cdd + ((size_t)n*K_ + wv)*D_);
    float s = 0.f;
    for (int dd = ln; dd < 100; dd += 64) {
      const float4 u = up[dd], c = cp[dd];
      s += u.x*c.x + u.y*c.y + u.z*c.z + u.w*c.w;
    }
    #pragma unroll
    for (int off = 32; off >= 1; off >>= 1) s += __shfl_down(s, off);
    if (ln == 0) sc[wv] = s;
  }

  float pl0 = 0.f, pl1 = 0.f, pl2 = 0.f, pl3 = 0.f;
  if (tid < E_) {
    const int e = tid;
    float a0 = 0.f, a1 = 0.f, a2 = 0.f, a3 = 0.f;
    #pragma unroll 4
    for (int c = 0; c < CW_; ++c) {
      const float w = W_lin[(size_t)(D_ + c)*E_ + e];
      a0 += cw[0][c]*w; a1 += cw[1][c]*w; a2 += cw[2][c]*w; a3 += cw[3][c]*w;
    }
    const float q = q_vec[e];
    const float* ue = ulin + (size_t)b*K_*E_ + e;
    pl0 = tanhf(ue[0*E_] + a0) * q;
    pl1 = tanhf(ue[1*E_] + a1) * q;
    pl2 = tanhf(ue[2*E_] + a2) * q;
    pl3 = tanhf(ue[3*E_] + a3) * q;
  }
  #pragma unroll
  for (int off = 1; off < 64; off <<= 1) {
    pl0 += __shfl_xor(pl0, off); pl1 += __shfl_xor(pl1, off);
    pl2 += __shfl_xor(pl2, off); pl3 += __shfl_xor(pl3, off);
  }
  if (ln == 0) { red[wv][0] = pl0; red[wv][1] = pl1; red[wv][2] = pl2; red[wv][3] = pl3; }
  __syncthreads();

  if (tid == 0) {
    const float l0 = red[0][0]+red[1][0]+red[2][0]+red[3][0];
    const float l1 = red[0][1]+red[1][1]+red[2][1]+red[3][1];
    const float l2 = red[0][2]+red[1][2]+red[2][2]+red[3][2];
    const float l3 = red[0][3]+red[1][3]+red[2][3]+red[3][3];
    const float m = fmaxf(fmaxf(l0, l1), fmaxf(l2, l3));
    const float e0 = expf(l0 - m), e1 = expf(l1 - m);
    const float e2 = expf(l2 - m), e3 = expf(l3 - m);
    const float s = e0 + e1 + e2 + e3;
    out[n] = (e0*sc[0] + e1*sc[1] + e2*sc[2] + e3*sc[3]) / s;
  }

  {
    const float4* ub4 = (const float4*)(u_b + (size_t)b*K_*D_);
    float4* uo = (float4*)(out + N_ + (size_t)n*K_*D_);
    for (int idx = tid; idx < 400; idx += 256) uo[idx] = ub4[idx];
  }
}

extern "C" void kernel_launch(void* const* d_in, const int* in_sizes, int n_in,
                              void* d_out, int out_size, void* d_ws, size_t ws_size,
                              hipStream_t stream) {
  const float* his   = (const float*)d_in[0];
  const float* cdd   = (const float*)d_in[1];
  const float* cwt   = (const float*)d_in[2];
  const float* W_att = (const float*)d_in[3];
  const float* b_att = (const float*)d_in[4];
  const float* q_att = (const float*)d_in[5];
  const float* W_lin = (const float*)d_in[6];
  const float* b_lin = (const float*)d_in[7];
  const float* q_vec = (const float*)d_in[8];
  float* out = (float*)d_out;

  float* ws   = (float*)d_ws;
  float* u_b  = ws;                                   // B*K*D = 204800 f
  float* ulin = u_b + (size_t)B_*K_*D_;               // B*K*E = 102400 f
  short* WT   = (short*)(ulin + (size_t)B_*K_*E_);    // 4*13*208*40 bf16

  k0_cast  <<<dim3(K_, NCH),  256, 0, stream>>>(W_att, WT);
  k12_fused<<<dim3(B_, K_),   512, 0, stream>>>(his, WT, b_att, q_att, W_lin, b_lin, u_b, ulin);
  k4_score <<<N_,             256, 0, stream>>>(cdd, cwt, W_lin, q_vec, u_b, ulin, out);
}

// Round 6
// 244.383 us; speedup vs baseline: 7.1232x; 1.0318x over previous
//
#include <hip/hip_runtime.h>
#include <hip/hip_bf16.h>
#include <math.h>

#define B_ 128
#define H_ 100
#define C_ 32
#define K_ 4
#define D_ 400
#define E_ 200
#define CW_ 100
#define N_ (B_*C_)
#define NCH 13            // K-chunks of 32 (416 padded)
#define MR_ 112           // valid M rows per block (100 + 12 pad), LDS holds 128

typedef short bf16x8 __attribute__((ext_vector_type(8)));
typedef float f32x16 __attribute__((ext_vector_type(16)));

__device__ __forceinline__ short f2b(float f) {
  union { float f; unsigned u; } x; x.f = f;
  unsigned r = x.u + 0x7fffu + ((x.u >> 16) & 1u);   // RNE
  return (short)(r >> 16);
}

__device__ __forceinline__ void gload_lds16(const void* g, void* l) {
  __builtin_amdgcn_global_load_lds((const __attribute__((address_space(1))) void*)g,
                                   (__attribute__((address_space(3))) void*)l, 16, 0, 0);
}

// ------------------------------------------------------------------
// k0: W_att -> WT bf16, chunk-major [k][c 13][col 208][j 40]
// (j = d-in-chunk: 32 valid + 8 zero; cols 200..207 zero)
// ------------------------------------------------------------------
__global__ __launch_bounds__(256) void k0_cast(const float* __restrict__ W_att,
                                               short* __restrict__ WT) {
  const int k = blockIdx.x, c = blockIdx.y;
  const int tid = threadIdx.x;
  __shared__ float Wst[32][200];
  for (int idx = tid; idx < 32*200; idx += 256) {
    const int j = idx / 200, col = idx % 200;
    const int d = c*32 + j;
    Wst[j][col] = (d < D_) ? W_att[((size_t)k*D_ + d)*E_ + col] : 0.f;
  }
  __syncthreads();
  short* dst = WT + (size_t)(k*NCH + c)*208*40;
  for (int idx = tid; idx < 208*40; idx += 256) {
    const int col = idx / 40, j = idx % 40;
    const float v = (col < E_ && j < 32) ? Wst[j][col] : 0.f;
    dst[idx] = f2b(v);
  }
}

// ------------------------------------------------------------------
// k12: per (b,k): logits GEMM (M=112->128, N=208->224, K=416) via
// 32x32x16 MFMA + in-block softmax + u_b + ulin.
// 8 waves = 4 M-tiles x 2 N-halves (wn0: tiles {0,2,4,6}, wn1: {1,3,5}).
// A reg-staged fp32->bf16 with 2-deep prefetch; B via global_load_lds.
// Al rows 112-127 / Bl rows 208-223 zero-filled ONCE at entry (staging
// never touches them; MFMA reads them -> must be defined). Epilogue
// skips e>=200 entirely (tanhf(garbage)*0 == NaN was the R5 bug).
// Fragment maps (32x32x16_bf16): A row=l&31, k=(l>>5)*8+j; B col=l&31,
// same k; C col=l&31, row=(reg&3)+8*(reg>>2)+4*(l>>5)  [m74/m101].
// ------------------------------------------------------------------
__global__ __launch_bounds__(512, 4) void k12_fused(const float* __restrict__ his,
                                                    const short* __restrict__ WT,
                                                    const float* __restrict__ b_att,
                                                    const float* __restrict__ q_att,
                                                    const float* __restrict__ W_lin,
                                                    const float* __restrict__ b_lin,
                                                    float* __restrict__ u_b,
                                                    float* __restrict__ ulin) {
  const int b = blockIdx.x, k = blockIdx.y;
  const int tid = threadIdx.x;
  const int w = tid >> 6, l = tid & 63;
  const int wm = w >> 1, wn = w & 1;
  const int ln32 = l & 31, hi = l >> 5;
  const int koct8 = hi * 8;

  __shared__ __align__(16) short Al[2][128][40];   // 20.5 KB
  __shared__ __align__(16) short Bl[2][224][40];   // 35.8 KB
  __shared__ float slp[2][MR_];
  __shared__ float sv[128];
  __shared__ float sa[H_];
  __shared__ float4 part[4][100];
  __shared__ float ul[D_];
  __shared__ float ulp[2][E_];

  f32x16 acc[4];
  #pragma unroll
  for (int t = 0; t < 4; ++t) acc[t] = (f32x16)(0.f);

  // zero-fill the never-staged LDS rows (read by MFMA as pad fragments)
  for (int i = tid; i < 16*40; i += 512) {
    const int r = i / 40, j = i % 40;
    Al[0][112 + r][j] = 0; Al[1][112 + r][j] = 0;
    Bl[0][208 + r][j] = 0; Bl[1][208 + r][j] = 0;
  }

  // A staging: 448 threads, arow = tid>>2 (0..111), aq = tid&3 (8 floats each)
  const int arow = tid >> 2, aq = tid & 3;
  const bool astage = (tid < 448);
  const float* hisrow = his + (((size_t)b*H_ + arow)*K_ + k)*D_;
  const short* WTk = WT + (size_t)k*NCH*8320;
  const int arow32 = wm*32 + ln32;
  const float4 zf4 = {0.f, 0.f, 0.f, 0.f};

#define ISSUE_A(cidx, r0, r1)                                           \
  { r0 = zf4; r1 = zf4;                                                 \
    const int d_ = (cidx)*32 + aq*8;                                    \
    if (astage && arow < H_ && d_ < D_) {                               \
      r0 = *(const float4*)(hisrow + d_);                               \
      r1 = *(const float4*)(hisrow + d_ + 4);                           \
    } }

#define CONV_A(bufdst, r0, r1)                                          \
  if (astage) {                                                         \
    short s8[8];                                                        \
    s8[0]=f2b(r0.x); s8[1]=f2b(r0.y); s8[2]=f2b(r0.z); s8[3]=f2b(r0.w); \
    s8[4]=f2b(r1.x); s8[5]=f2b(r1.y); s8[6]=f2b(r1.z); s8[7]=f2b(r1.w); \
    *(bf16x8*)&Al[bufdst][arow][aq*8] = *(bf16x8*)s8;                   \
  }

#define DMA_B(cidx, bufdst)                                             \
  { const short* src_ = WTk + (size_t)(cidx)*8320;                      \
    for (int i_ = tid; i_ < 1040; i_ += 512)                            \
      gload_lds16(src_ + i_*8, (short*)&Bl[bufdst][0][0] + i_*8); }

#define COMPUTE(bufc)                                                   \
  { const bf16x8 af0 = *(const bf16x8*)&Al[bufc][arow32][koct8];        \
    const bf16x8 af1 = *(const bf16x8*)&Al[bufc][arow32][16 + koct8];   \
    _Pragma("unroll")                                                   \
    for (int t = 0; t < 4; ++t) {                                       \
      if (2*t + wn < 7) {                                               \
        const int col = (wn + 2*t)*32 + ln32;                           \
        const bf16x8 bf0 = *(const bf16x8*)&Bl[bufc][col][koct8];       \
        acc[t] = __builtin_amdgcn_mfma_f32_32x32x16_bf16(af0, bf0, acc[t], 0, 0, 0); \
        const bf16x8 bf1 = *(const bf16x8*)&Bl[bufc][col][16 + koct8];  \
        acc[t] = __builtin_amdgcn_mfma_f32_32x32x16_bf16(af1, bf1, acc[t], 0, 0, 0); \
      } } }

  float4 pa0, pa1, pb0, pb1;
  // prologue
  ISSUE_A(0, pa0, pa1);
  ISSUE_A(1, pb0, pb1);
  DMA_B(0, 0);
  CONV_A(0, pa0, pa1);
  __syncthreads();

  for (int c = 0; c < NCH; c += 2) {
    // even chunk c (buf 0)
    if (c + 2 < NCH) ISSUE_A(c+2, pa0, pa1);
    if (c + 1 < NCH) DMA_B(c+1, 1);
    COMPUTE(0);
    if (c + 1 < NCH) { CONV_A(1, pb0, pb1); __syncthreads(); }
    // odd chunk c+1 (buf 1)
    if (c + 1 < NCH) {
      if (c + 3 < NCH) ISSUE_A(c+3, pb0, pb1);
      if (c + 2 < NCH) DMA_B(c+2, 0);
      COMPUTE(1);
      if (c + 2 < NCH) { CONV_A(0, pa0, pa1); __syncthreads(); }
    }
  }

  // ---- epilogue: p[row] = sum_e tanh(C + b_att[e]) * q_att[e] ----
  {
    float p[16];
    #pragma unroll
    for (int r = 0; r < 16; ++r) p[r] = 0.f;
    #pragma unroll
    for (int t = 0; t < 4; ++t) {
      if (2*t + wn < 7) {
        const int e = (wn + 2*t)*32 + ln32;
        if (e < E_) {                       // skip pad cols ENTIRELY (R5 bug)
          const float q  = q_att[k*E_ + e];
          const float bb = b_att[k*E_ + e];
          #pragma unroll
          for (int r = 0; r < 16; ++r) {
            const int row = wm*32 + (r&3) + 8*(r>>2) + 4*hi;
            if (row < H_) p[r] += tanhf(acc[t][r] + bb) * q;
          }
        }
      }
    }
    #pragma unroll
    for (int off = 1; off < 32; off <<= 1)
      #pragma unroll
      for (int r = 0; r < 16; ++r) p[r] += __shfl_xor(p[r], off);
    if (ln32 == 0) {
      #pragma unroll
      for (int r = 0; r < 16; ++r) {
        const int row = wm*32 + (r&3) + 8*(r>>2) + 4*hi;
        if (row < MR_) slp[wn][row] = p[r];
      }
    }
  }
  __syncthreads();

  // ---- softmax over h<100 ----
  const float v = (tid < H_) ? slp[0][tid] + slp[1][tid] : -INFINITY;
  if (tid < 128) sv[tid] = v;
  __syncthreads();
  for (int s = 64; s > 0; s >>= 1) { if (tid < s) sv[tid] = fmaxf(sv[tid], sv[tid+s]); __syncthreads(); }
  const float mx = sv[0];
  __syncthreads();
  const float ev = (tid < H_) ? expf(v - mx) : 0.f;
  if (tid < 128) sv[tid] = ev;
  __syncthreads();
  for (int s = 64; s > 0; s >>= 1) { if (tid < s) sv[tid] += sv[tid+s]; __syncthreads(); }
  const float inv = 1.f / sv[0];
  if (tid < H_) sa[tid] = ev * inv;
  __syncthreads();

  // ---- u_b = a . his (fp32, L2-hot re-read), 4 h-groups x 25 ----
  const int gg = tid / 100, d4 = tid % 100;
  if (tid < 400) {
    float4 a4 = {0.f, 0.f, 0.f, 0.f};
    const float* hp = his + (((size_t)b*H_ + gg*25)*K_ + k)*D_ + d4*4;
    #pragma unroll 5
    for (int h = 0; h < 25; ++h) {
      const float4 x = *(const float4*)(hp + (size_t)h*K_*D_);
      const float ww = sa[gg*25 + h];
      a4.x += ww*x.x; a4.y += ww*x.y; a4.z += ww*x.z; a4.w += ww*x.w;
    }
    part[gg][d4] = a4;
  }
  __syncthreads();
  if (tid < 100) {
    const float4 p0 = part[0][tid], p1 = part[1][tid], p2 = part[2][tid], p3 = part[3][tid];
    float4 a4;
    a4.x = p0.x+p1.x+p2.x+p3.x; a4.y = p0.y+p1.y+p2.y+p3.y;
    a4.z = p0.z+p1.z+p2.z+p3.z; a4.w = p0.w+p1.w+p2.w+p3.w;
    *(float4*)&ul[tid*4] = a4;
    *(float4*)(u_b + ((size_t)b*K_ + k)*D_ + tid*4) = a4;
  }
  __syncthreads();

  // ---- ulin = u_b . W_lin[:D] + b_lin (d split in halves) ----
  if (tid < 400) {
    const int dg = tid / 200, e = tid % 200;
    const int dbase = dg * 200;
    float c0 = 0.f, c1 = 0.f, c2 = 0.f, c3 = 0.f;
    #pragma unroll 2
    for (int d = 0; d < 200; d += 4) {
      c0 += ul[dbase+d]   * W_lin[(size_t)(dbase+d)*E_     + e];
      c1 += ul[dbase+d+1] * W_lin[(size_t)(dbase+d+1)*E_ + e];
      c2 += ul[dbase+d+2] * W_lin[(size_t)(dbase+d+2)*E_ + e];
      c3 += ul[dbase+d+3] * W_lin[(size_t)(dbase+d+3)*E_ + e];
    }
    ulp[dg][e] = c0 + c1 + c2 + c3;
  }
  __syncthreads();
  if (tid < E_)
    ulin[((size_t)b*K_ + k)*E_ + tid] = ulp[0][tid] + ulp[1][tid] + b_lin[tid];
}

// ------------------------------------------------------------------
// k4: 4 candidates per block. W_lin[D+c] load feeds 16 FMAs.
// ------------------------------------------------------------------
__global__ __launch_bounds__(256) void k4_score(const float* __restrict__ cdd,
                                                const float* __restrict__ cwt,
                                                const float* __restrict__ W_lin,
                                                const float* __restrict__ q_vec,
                                                const float* __restrict__ u_b,
                                                const float* __restrict__ ulin,
                                                float* __restrict__ out) {
  const int n0 = blockIdx.x * 4;
  const int b  = n0 >> 5;                  // all 4 n share b (32 % 4 == 0)
  const int tid = threadIdx.x;
  const int wv = tid >> 6, ln = tid & 63;
  __shared__ float cw[4][K_][CW_];
  __shared__ float red[4][4][K_];
  __shared__ float sc[4][K_];

  {
    const float4* src = (const float4*)(cwt + (size_t)n0*K_*CW_);
    float4* dst = (float4*)&cw[0][0][0];
    for (int idx = tid; idx < 400; idx += 256) dst[idx] = src[idx];
  }
  __syncthreads();

  // candidate scores: wave wv owns candidate n0+wv, all 4 k
  {
    const float4* up = (const float4*)(u_b + (size_t)b*K_*D_);
    const float4* cp = (const float4*)(cdd + (size_t)(n0 + wv)*K_*D_);
    #pragma unroll
    for (int kk = 0; kk < K_; ++kk) {
      float s = 0.f;
      for (int dd = ln; dd < 100; dd += 64) {
        const float4 u = up[kk*100 + dd], c = cp[kk*100 + dd];
        s += u.x*c.x + u.y*c.y + u.z*c.z + u.w*c.w;
      }
      #pragma unroll
      for (int off = 32; off >= 1; off >>= 1) s += __shfl_down(s, off);
      if (ln == 0) sc[wv][kk] = s;
    }
  }

  // cl[n][k] for this thread's e + logit partials
  float pl[4][K_];
  #pragma unroll
  for (int n4 = 0; n4 < 4; ++n4)
    #pragma unroll
    for (int kk = 0; kk < K_; ++kk) pl[n4][kk] = 0.f;

  if (tid < E_) {
    const int e = tid;
    float a[4][K_];
    #pragma unroll
    for (int n4 = 0; n4 < 4; ++n4)
      #pragma unroll
      for (int kk = 0; kk < K_; ++kk) a[n4][kk] = 0.f;
    #pragma unroll 2
    for (int c = 0; c < CW_; ++c) {
      const float wlc = W_lin[(size_t)(D_ + c)*E_ + e];
      #pragma unroll
      for (int n4 = 0; n4 < 4; ++n4)
        #pragma unroll
        for (int kk = 0; kk < K_; ++kk)
          a[n4][kk] += cw[n4][kk][c] * wlc;
    }
    const float q = q_vec[e];
    float ue[K_];
    #pragma unroll
    for (int kk = 0; kk < K_; ++kk) ue[kk] = ulin[((size_t)b*K_ + kk)*E_ + e];
    #pragma unroll
    for (int n4 = 0; n4 < 4; ++n4)
      #pragma unroll
      for (int kk = 0; kk < K_; ++kk)
        pl[n4][kk] = tanhf(ue[kk] + a[n4][kk]) * q;
  }
  #pragma unroll
  for (int off = 1; off < 64; off <<= 1)
    #pragma unroll
    for (int n4 = 0; n4 < 4; ++n4)
      #pragma unroll
      for (int kk = 0; kk < K_; ++kk) pl[n4][kk] += __shfl_xor(pl[n4][kk], off);
  if (ln == 0) {
    #pragma unroll
    for (int n4 = 0; n4 < 4; ++n4)
      #pragma unroll
      for (int kk = 0; kk < K_; ++kk) red[wv][n4][kk] = pl[n4][kk];
  }
  __syncthreads();

  if (tid < 4) {
    float lg[K_];
    #pragma unroll
    for (int kk = 0; kk < K_; ++kk)
      lg[kk] = red[0][tid][kk] + red[1][tid][kk] + red[2][tid][kk] + red[3][tid][kk];
    const float m = fmaxf(fmaxf(lg[0], lg[1]), fmaxf(lg[2], lg[3]));
    const float e0 = expf(lg[0]-m), e1 = expf(lg[1]-m);
    const float e2 = expf(lg[2]-m), e3 = expf(lg[3]-m);
    const float s = e0 + e1 + e2 + e3;
    out[n0 + tid] = (e0*sc[tid][0] + e1*sc[tid][1] + e2*sc[tid][2] + e3*sc[tid][3]) / s;
  }

  // u_channel: broadcast u_b[b] to the 4 candidates
  {
    const float4* ub4 = (const float4*)(u_b + (size_t)b*K_*D_);
    for (int idx = tid; idx < 1600; idx += 256) {
      const int n4 = idx / 400, off = idx % 400;
      *((float4*)(out + N_ + (size_t)(n0 + n4)*K_*D_) + off) = ub4[off];
    }
  }
}

extern "C" void kernel_launch(void* const* d_in, const int* in_sizes, int n_in,
                              void* d_out, int out_size, void* d_ws, size_t ws_size,
                              hipStream_t stream) {
  const float* his   = (const float*)d_in[0];
  const float* cdd   = (const float*)d_in[1];
  const float* cwt   = (const float*)d_in[2];
  const float* W_att = (const float*)d_in[3];
  const float* b_att = (const float*)d_in[4];
  const float* q_att = (const float*)d_in[5];
  const float* W_lin = (const float*)d_in[6];
  const float* b_lin = (const float*)d_in[7];
  const float* q_vec = (const float*)d_in[8];
  float* out = (float*)d_out;

  float* ws   = (float*)d_ws;
  float* u_b  = ws;                                   // B*K*D = 204800 f
  float* ulin = u_b + (size_t)B_*K_*D_;               // B*K*E = 102400 f
  short* WT   = (short*)(ulin + (size_t)B_*K_*E_);    // 4*13*208*40 bf16

  k0_cast  <<<dim3(K_, NCH),  256, 0, stream>>>(W_att, WT);
  k12_fused<<<dim3(B_, K_),   512, 0, stream>>>(his, WT, b_att, q_att, W_lin, b_lin, u_b, ulin);
  k4_score <<<N_/4,           256, 0, stream>>>(cdd, cwt, W_lin, q_vec, u_b, ulin, out);
}